// Round 3
// baseline (636.469 us; speedup 1.0000x reference)
//
#include <hip/hip_runtime.h>
#include <cfloat>
#include <cstdint>

// ---------------- problem constants ----------------
#define B_BATCH 32
#define D_DIM   256
#define HW      1024          // 32*32
#define N_POS   32768         // B_BATCH * HW
#define K_CODES 1024
#define DECAY_F   0.99f
#define ONE_M_DECAY 0.01f
#define EPS_F   1e-5f

// ---------------- output layout (floats) ----------------
#define OUT_Q    0                         // 8388608  quantized_st (B,C,H,W)
#define OUT_LOSS 8388608                   // 1
#define OUT_PERP 8388609                   // 1
#define OUT_CB   8388610                   // 262144   new_codebook
#define OUT_NCS  8650754                   // 1024     new_cluster_size
#define OUT_EDW  8651778                   // 262144   new_ema_dw (dw scratch first)

// NOTE: OUT_Q region doubles as z_t[n][d] scratch (exactly 8388608 floats):
// ztrans writes it, argmin+dw read it, fuse overwrites it with the real output.

// ---------------- workspace layout (bytes) ----------------
#define WS_COUNTS  0          // 1024*4
#define WS_LOSS    4096       // 4
#define WS_NTOT    4100       // 4
#define WS_MEMSET  4104       // bytes to zero at launch
#define WS_CBNORM  4352       // 1024*4
#define WS_OFFS    8448       // 1024*4 (int)
#define WS_CURSOR  12544      // 1024*4 (int)
#define WS_IDX     16640      // 32768*4 (int)
#define WS_SORTED  147712     // 32768*4 (int)
#define WS_CBHI    278784     // 262144*2 (ushort bf16 bits)
#define WS_CBLO    803072     // 262144*2
#define WS_TOTAL   1327360

typedef short s16x8 __attribute__((ext_vector_type(8)));
typedef float f32x4 __attribute__((ext_vector_type(4)));

__device__ __forceinline__ ushort f2bf_rne(float x) {
    uint u = __float_as_uint(x);
    uint r = (u + 0x7FFF + ((u >> 16) & 1)) >> 16;
    return (ushort)r;
}
__device__ __forceinline__ float bf2f(ushort h) {
    return __uint_as_float(((uint)h) << 16);
}

// ============================================================
// cbprep: codebook fp32 -> bf16 hi/lo bit arrays.
__global__ __launch_bounds__(256) void cbprep_kernel(const float* __restrict__ cb,
                                                     ushort* __restrict__ hi,
                                                     ushort* __restrict__ lo) {
    int i = (blockIdx.x * 256 + threadIdx.x) * 4;
    float4 v = *(const float4*)&cb[i];
    ushort4 h, l;
    h.x = f2bf_rne(v.x); l.x = f2bf_rne(v.x - bf2f(h.x));
    h.y = f2bf_rne(v.y); l.y = f2bf_rne(v.y - bf2f(h.y));
    h.z = f2bf_rne(v.z); l.z = f2bf_rne(v.z - bf2f(h.z));
    h.w = f2bf_rne(v.w); l.w = f2bf_rne(v.w - bf2f(h.w));
    *(ushort4*)&hi[i] = h;
    *(ushort4*)&lo[i] = l;
}

// ============================================================
// cbnorm: codebook row squared norms (fp32 exact). One wave per code.
__global__ __launch_bounds__(256) void cbnorm_kernel(const float* __restrict__ cb,
                                                     float* __restrict__ cbnorm) {
    int wave = threadIdx.x >> 6;
    int lane = threadIdx.x & 63;
    int k = blockIdx.x * 4 + wave;
    const float* row = cb + (size_t)k * D_DIM;
    float s = 0.f;
    #pragma unroll
    for (int j = 0; j < 4; ++j) {
        float v = row[lane + 64 * j];
        s += v * v;
    }
    #pragma unroll
    for (int off = 32; off >= 1; off >>= 1) s += __shfl_xor(s, off);
    if (lane == 0) cbnorm[k] = s;
}

// ============================================================
// ztrans: z (B,C,H,W i.e. d-major) -> z_t[n][d] (position-major fp32),
// written into the OUT_Q region as scratch.
__global__ __launch_bounds__(256) void ztrans_kernel(const float* __restrict__ z,
                                                     float* __restrict__ z_t) {
    __shared__ float Zs[32][65];
    const int tid = threadIdx.x;
    const int n0  = blockIdx.x * 64;
    const int b   = n0 >> 10;
    const int hw0 = n0 & 1023;
    const float* zb = z + (size_t)b * (D_DIM * HW) + hw0;

    const int zn = tid & 63;
    const int zdb = (tid >> 6) * 8;
    const int n  = tid >> 2;
    const int dqg = tid & 3;

    for (int d0 = 0; d0 < D_DIM; d0 += 32) {
        __syncthreads();
        #pragma unroll
        for (int j = 0; j < 8; ++j)
            Zs[zdb + j][zn] = zb[(size_t)(d0 + zdb + j) * HW + zn];
        __syncthreads();
        float4 v0, v1;
        v0.x = Zs[dqg * 8 + 0][n]; v0.y = Zs[dqg * 8 + 1][n];
        v0.z = Zs[dqg * 8 + 2][n]; v0.w = Zs[dqg * 8 + 3][n];
        v1.x = Zs[dqg * 8 + 4][n]; v1.y = Zs[dqg * 8 + 5][n];
        v1.z = Zs[dqg * 8 + 6][n]; v1.w = Zs[dqg * 8 + 7][n];
        *(float4*)&z_t[(size_t)(n0 + n) * D_DIM + d0 + dqg * 8]     = v0;
        *(float4*)&z_t[(size_t)(n0 + n) * D_DIM + d0 + dqg * 8 + 4] = v1;
    }
}

// ============================================================
// argmin via MFMA (3-term bf16 split). Block = 64 positions, 4 waves.
// A = codebook (M=codes), B = positions; D[m][n]: col=lane&15 -> position,
// row=(lane>>4)*4+reg -> code. B-frags (hi+lo, full D) live in 64 VGPRs.
__global__ __launch_bounds__(256) void argmin_mfma(const float* __restrict__ z_t,
                                                   const ushort* __restrict__ cbhi,
                                                   const ushort* __restrict__ cblo,
                                                   const float* __restrict__ cbnorm,
                                                   int* __restrict__ idx_out,
                                                   float* __restrict__ counts) {
    __shared__ float Zt[64 * 132];   // half-D staging, row pad 132 dwords
    __shared__ float cbn_s[1024];

    const int tid = threadIdx.x;
    const int wave = tid >> 6;
    const int lane = tid & 63;
    const int col = lane & 15;
    const int lg  = lane >> 4;
    const int n0 = blockIdx.x * 64;

    for (int i = tid; i < 1024; i += 256) cbn_s[i] = cbnorm[i];

    s16x8 bhi[8], blo[8];

    for (int half = 0; half < 2; ++half) {
        __syncthreads();
        #pragma unroll
        for (int it = 0; it < 8; ++it) {
            int flatid = it * 256 + tid;
            int row = flatid >> 5;      // 32 float4 per row-half
            int c4 = flatid & 31;
            *(float4*)&Zt[row * 132 + c4 * 4] =
                *(const float4*)&z_t[(size_t)(n0 + row) * D_DIM + half * 128 + c4 * 4];
        }
        __syncthreads();
        int rowL = wave * 16 + col;
        #pragma unroll
        for (int dc = 0; dc < 4; ++dc) {
            float f[8];
            *(float4*)&f[0] = *(const float4*)&Zt[rowL * 132 + dc * 32 + lg * 8];
            *(float4*)&f[4] = *(const float4*)&Zt[rowL * 132 + dc * 32 + lg * 8 + 4];
            s16x8 h, l;
            #pragma unroll
            for (int j = 0; j < 8; ++j) {
                ushort hb = f2bf_rne(f[j]);
                float r = f[j] - bf2f(hb);
                ushort lb = f2bf_rne(r);
                h[j] = (short)hb;
                l[j] = (short)lb;
            }
            bhi[half * 4 + dc] = h;
            blo[half * 4 + dc] = l;
        }
    }

    float bestd = FLT_MAX;
    int bestk = 0;

    for (int kt = 0; kt < 64; kt += 2) {
        f32x4 acc0 = {0.f, 0.f, 0.f, 0.f};
        f32x4 acc1 = {0.f, 0.f, 0.f, 0.f};
        const size_t a0 = (size_t)(kt * 16 + col) * D_DIM + lg * 8;
        const size_t a1 = a0 + 16 * D_DIM;
        #pragma unroll
        for (int dc = 0; dc < 8; ++dc) {
            s16x8 a0h = *(const s16x8*)&cbhi[a0 + dc * 32];
            s16x8 a0l = *(const s16x8*)&cblo[a0 + dc * 32];
            s16x8 a1h = *(const s16x8*)&cbhi[a1 + dc * 32];
            s16x8 a1l = *(const s16x8*)&cblo[a1 + dc * 32];
            acc0 = __builtin_amdgcn_mfma_f32_16x16x32_bf16(a0h, bhi[dc], acc0, 0, 0, 0);
            acc1 = __builtin_amdgcn_mfma_f32_16x16x32_bf16(a1h, bhi[dc], acc1, 0, 0, 0);
            acc0 = __builtin_amdgcn_mfma_f32_16x16x32_bf16(a0h, blo[dc], acc0, 0, 0, 0);
            acc1 = __builtin_amdgcn_mfma_f32_16x16x32_bf16(a1h, blo[dc], acc1, 0, 0, 0);
            acc0 = __builtin_amdgcn_mfma_f32_16x16x32_bf16(a0l, bhi[dc], acc0, 0, 0, 0);
            acc1 = __builtin_amdgcn_mfma_f32_16x16x32_bf16(a1l, bhi[dc], acc1, 0, 0, 0);
        }
        #pragma unroll
        for (int r = 0; r < 4; ++r) {
            int k0 = kt * 16 + lg * 4 + r;
            float d0 = cbn_s[k0] - 2.f * acc0[r];
            if (d0 < bestd) { bestd = d0; bestk = k0; }
        }
        #pragma unroll
        for (int r = 0; r < 4; ++r) {
            int k1 = (kt + 1) * 16 + lg * 4 + r;
            float d1 = cbn_s[k1] - 2.f * acc1[r];
            if (d1 < bestd) { bestd = d1; bestk = k1; }
        }
    }

    // reduce across the 4 lane-groups holding the same position (xor 16, 32)
    #pragma unroll
    for (int off = 16; off <= 32; off <<= 1) {
        float od = __shfl_xor(bestd, off);
        int ok = __shfl_xor(bestk, off);
        if (od < bestd || (od == bestd && ok < bestk)) { bestd = od; bestk = ok; }
    }
    if (lane < 16) {
        int n = n0 + wave * 16 + lane;
        idx_out[n] = bestk;
        atomicAdd(&counts[bestk], 1.f);
    }
}

// ============================================================
// Scan: exclusive prefix sum of counts -> offsets + cursor copy.
__global__ __launch_bounds__(1024) void scan_kernel(const float* __restrict__ counts,
                                                    int* __restrict__ offsets,
                                                    int* __restrict__ cursor) {
    __shared__ int s[1024];
    int k = threadIdx.x;
    int c = (int)counts[k];
    s[k] = c;
    __syncthreads();
    for (int off = 1; off < 1024; off <<= 1) {
        int v = (k >= off) ? s[k - off] : 0;
        __syncthreads();
        s[k] += v;
        __syncthreads();
    }
    int excl = s[k] - c;
    offsets[k] = excl;
    cursor[k] = excl;
}

// ============================================================
// Scatter: bucket position ids by code.
__global__ __launch_bounds__(256) void scatter_kernel(const int* __restrict__ idx,
                                                      int* __restrict__ cursor,
                                                      int* __restrict__ sorted) {
    int n = blockIdx.x * 256 + threadIdx.x;
    int k = idx[n];
    int pos = atomicAdd(&cursor[k], 1);
    sorted[pos] = n;
}

// ============================================================
// dw: one block per code; segmented sum over sorted positions (z_t rows).
__global__ __launch_bounds__(256) void dw_kernel(const float* __restrict__ z_t,
                                                 const int* __restrict__ sorted,
                                                 const int* __restrict__ offsets,
                                                 const float* __restrict__ counts,
                                                 float* __restrict__ dw) {
    __shared__ float part[4][256];
    const int k = blockIdx.x;
    const int start = offsets[k];
    const int cnt = (int)counts[k];
    const int w = threadIdx.x >> 6;
    const int lane = threadIdx.x & 63;

    float4 acc = {0.f, 0.f, 0.f, 0.f};
    for (int p = start + w; p < start + cnt; p += 4) {
        int id = sorted[p];
        float4 v = *(const float4*)&z_t[(size_t)id * D_DIM + lane * 4];
        acc.x += v.x; acc.y += v.y; acc.z += v.z; acc.w += v.w;
    }
    part[w][lane * 4 + 0] = acc.x;
    part[w][lane * 4 + 1] = acc.y;
    part[w][lane * 4 + 2] = acc.z;
    part[w][lane * 4 + 3] = acc.w;
    __syncthreads();
    int d = threadIdx.x;
    dw[(size_t)k * D_DIM + d] = part[0][d] + part[1][d] + part[2][d] + part[3][d];
}

// ============================================================
// Fuse: read z -> write outq (straight-through), accumulate loss.
// Runs AFTER dw (overwrites the z_t scratch living in OUT_Q).
__global__ __launch_bounds__(256) void fuse_kernel(const float* __restrict__ z,
                                                   const float* __restrict__ cb,
                                                   const int* __restrict__ idx,
                                                   float* __restrict__ outq,
                                                   float* __restrict__ lossacc) {
    __shared__ float Zs[32][65];
    __shared__ float Qs[32][65];
    __shared__ int kidx[64];
    __shared__ float red[256];

    const int tid = threadIdx.x;
    const int n0  = blockIdx.x * 64;
    const int b   = n0 >> 10;
    const int hw0 = n0 & 1023;
    const float* zb = z    + (size_t)b * (D_DIM * HW) + hw0;
    float*       ob = outq + (size_t)b * (D_DIM * HW) + hw0;

    if (tid < 64) kidx[tid] = idx[n0 + tid];

    const int zn = tid & 63;
    const int zdb = (tid >> 6) * 8;
    float loss = 0.f;

    for (int d0 = 0; d0 < D_DIM; d0 += 32) {
        __syncthreads();
        #pragma unroll
        for (int j = 0; j < 8; ++j)
            Zs[zdb + j][zn] = zb[(size_t)(d0 + zdb + j) * HW + zn];
        __syncthreads();

        #pragma unroll
        for (int h = 0; h < 2; ++h) {
            int s  = tid + 256 * h;
            int n  = s >> 3;
            int dq = s & 7;
            int k  = kidx[n];
            float4 q = *(const float4*)&cb[(size_t)k * D_DIM + d0 + dq * 4];
            float zx = Zs[dq * 4 + 0][n];
            float zy = Zs[dq * 4 + 1][n];
            float zz2 = Zs[dq * 4 + 2][n];
            float zw = Zs[dq * 4 + 3][n];
            Qs[dq * 4 + 0][n] = q.x;
            Qs[dq * 4 + 1][n] = q.y;
            Qs[dq * 4 + 2][n] = q.z;
            Qs[dq * 4 + 3][n] = q.w;
            float dx = zx - q.x, dy = zy - q.y, dz = zz2 - q.z, dww = zw - q.w;
            loss += dx * dx + dy * dy + dz * dz + dww * dww;
        }
        __syncthreads();

        #pragma unroll
        for (int j = 0; j < 8; ++j) {
            int v = tid + 256 * j;
            int d = v >> 6;
            int n = v & 63;
            float qq = Qs[d][n];
            float zval = Zs[d][n];
            ob[(size_t)(d0 + d) * HW + n] = zval + (qq - zval);
        }
    }

    red[tid] = loss;
    __syncthreads();
    for (int s2 = 128; s2 >= 1; s2 >>= 1) {
        if (tid < s2) red[tid] += red[tid + s2];
        __syncthreads();
    }
    if (tid == 0) atomicAdd(lossacc, red[0]);
}

// ============================================================
// finalize_small: new_cluster_size, n_total, perplexity, loss. One block.
__global__ __launch_bounds__(1024) void finalize_small(const float* __restrict__ ema_cs,
                                                       const float* __restrict__ counts,
                                                       const float* __restrict__ lossacc,
                                                       float* __restrict__ out_ncs,
                                                       float* __restrict__ out_loss,
                                                       float* __restrict__ out_perp,
                                                       float* __restrict__ ntot_ws) {
    __shared__ float s1[1024];
    __shared__ float s2[1024];
    int k = threadIdx.x;
    float cnt = counts[k];
    float ncs = ema_cs[k] * DECAY_F + ONE_M_DECAY * cnt;
    out_ncs[k] = ncs;
    float p = cnt / (float)N_POS;
    float pl = p * logf(p + 1e-10f);
    s1[k] = ncs;
    s2[k] = pl;
    __syncthreads();
    for (int s = 512; s >= 1; s >>= 1) {
        if (k < s) { s1[k] += s1[k + s]; s2[k] += s2[k + s]; }
        __syncthreads();
    }
    if (k == 0) {
        ntot_ws[0] = s1[0];
        out_perp[0] = expf(-s2[0]);
        out_loss[0] = 0.25f * lossacc[0] / 8388608.0f;
    }
}

// ============================================================
// finalize_rows: new_ema_dw (in place) and new_codebook.
__global__ __launch_bounds__(256) void finalize_rows(const float* __restrict__ ema_dw,
                                                     const float* __restrict__ out_ncs,
                                                     const float* __restrict__ ntot_ws,
                                                     float* __restrict__ out_edw,
                                                     float* __restrict__ out_cb) {
    int k = blockIdx.x;
    int d = threadIdx.x;
    float ncs = out_ncs[k];
    float nt = ntot_ws[0];
    float csz = (ncs + EPS_F) / (nt + (float)K_CODES * EPS_F) * nt;
    size_t e = (size_t)k * D_DIM + d;
    float ed = ema_dw[e] * DECAY_F + ONE_M_DECAY * out_edw[e];
    out_edw[e] = ed;
    out_cb[e] = ed / csz;
}

// ============================================================
extern "C" void kernel_launch(void* const* d_in, const int* in_sizes, int n_in,
                              void* d_out, int out_size, void* d_ws, size_t ws_size,
                              hipStream_t stream) {
    const float* z       = (const float*)d_in[0];
    const float* cb      = (const float*)d_in[1];
    const float* ema_cs  = (const float*)d_in[2];
    const float* ema_dw  = (const float*)d_in[3];
    float* out = (float*)d_out;

    char* ws = (char*)d_ws;
    float* ws_counts = (float*)(ws + WS_COUNTS);
    float* ws_loss   = (float*)(ws + WS_LOSS);
    float* ws_ntot   = (float*)(ws + WS_NTOT);
    float* ws_cbnorm = (float*)(ws + WS_CBNORM);
    int*   ws_offs   = (int*)(ws + WS_OFFS);
    int*   ws_cursor = (int*)(ws + WS_CURSOR);
    int*   ws_idx    = (int*)(ws + WS_IDX);
    int*   ws_sorted = (int*)(ws + WS_SORTED);
    ushort* ws_cbhi  = (ushort*)(ws + WS_CBHI);
    ushort* ws_cblo  = (ushort*)(ws + WS_CBLO);

    float* zt = out + OUT_Q;   // z_t scratch lives in the OUT_Q region

    hipMemsetAsync(d_ws, 0, WS_MEMSET, stream);

    cbprep_kernel<<<K_CODES * D_DIM / 1024, 256, 0, stream>>>(cb, ws_cbhi, ws_cblo);
    cbnorm_kernel<<<K_CODES / 4, 256, 0, stream>>>(cb, ws_cbnorm);
    ztrans_kernel<<<N_POS / 64, 256, 0, stream>>>(z, zt);
    argmin_mfma<<<N_POS / 64, 256, 0, stream>>>(zt, ws_cbhi, ws_cblo, ws_cbnorm,
                                                ws_idx, ws_counts);
    scan_kernel<<<1, 1024, 0, stream>>>(ws_counts, ws_offs, ws_cursor);
    scatter_kernel<<<N_POS / 256, 256, 0, stream>>>(ws_idx, ws_cursor, ws_sorted);
    dw_kernel<<<K_CODES, 256, 0, stream>>>(zt, ws_sorted, ws_offs, ws_counts,
                                           out + OUT_EDW);
    fuse_kernel<<<N_POS / 64, 256, 0, stream>>>(z, cb, ws_idx, out + OUT_Q, ws_loss);
    finalize_small<<<1, 1024, 0, stream>>>(
        ema_cs, ws_counts, ws_loss, out + OUT_NCS, out + OUT_LOSS, out + OUT_PERP, ws_ntot);
    finalize_rows<<<K_CODES, 256, 0, stream>>>(
        ema_dw, out + OUT_NCS, ws_ntot, out + OUT_EDW, out + OUT_CB);
}

// Round 4
// 392.788 us; speedup vs baseline: 1.6204x; 1.6204x over previous
//
#include <hip/hip_runtime.h>
#include <cfloat>
#include <cstdint>

// ---------------- problem constants ----------------
#define B_BATCH 32
#define D_DIM   256
#define HW      1024
#define N_POS   32768
#define K_CODES 1024
#define DECAY_F   0.99f
#define ONE_M_DECAY 0.01f
#define EPS_F   1e-5f

// ---------------- output layout (floats) ----------------
#define OUT_Q    0                         // 8388608  quantized_st (B,C,H,W)
#define OUT_LOSS 8388608                   // 1
#define OUT_PERP 8388609                   // 1
#define OUT_CB   8388610                   // 262144   new_codebook
#define OUT_NCS  8650754                   // 1024     new_cluster_size
#define OUT_EDW  8651778                   // 262144   new_ema_dw (dw scratch first)

// OUT_Q region doubles as z bf16 hi/lo scratch (exactly 33,554,432 bytes):
// ztrans writes zhi (16 MB) + zlo (16 MB); argmin_gemm + dw read them;
// fuse overwrites the region with the real output at the end.

// ---------------- workspace layout (bytes) ----------------
#define WS_COUNTS  0          // 1024*4
#define WS_LOSS    4096       // 4
#define WS_NTOT    4100       // 4
#define WS_MEMSET  4104       // bytes zeroed at launch
#define WS_CBNORM  4352       // 1024*4
#define WS_OFFS    8448       // 1024*4 (int)
#define WS_CURSOR  12544      // 1024*4 (int)
#define WS_IDX     16640      // 32768*4 (int)
#define WS_SORTED  147712     // 32768*4 (int)
#define WS_CBHI    278784     // 262144*2
#define WS_CBLO    803072     // 262144*2
#define WS_PART    1327360    // 32768*8*8 = 2097152 (u64 partial keys)
#define WS_TOTAL   3424512

typedef short s16x8 __attribute__((ext_vector_type(8)));
typedef float f32x4 __attribute__((ext_vector_type(4)));
typedef unsigned long long u64;

__device__ __forceinline__ ushort f2bf_rne(float x) {
    uint u = __float_as_uint(x);
    uint r = (u + 0x7FFF + ((u >> 16) & 1)) >> 16;
    return (ushort)r;
}
__device__ __forceinline__ float bf2f(ushort h) {
    return __uint_as_float(((uint)h) << 16);
}

// async global->LDS, 16 B per lane; LDS dst = wave-uniform base + lane*16
__device__ __forceinline__ void gload16(const void* g, void* l) {
    __builtin_amdgcn_global_load_lds(
        (const __attribute__((address_space(1))) unsigned*)(uintptr_t)g,
        (__attribute__((address_space(3))) unsigned*)(uintptr_t)l, 16, 0, 0);
}

// ============================================================
// prep: codebook fp32 -> bf16 hi/lo + row squared norms. One wave per code.
__global__ __launch_bounds__(256) void prep_kernel(const float* __restrict__ cb,
                                                   ushort* __restrict__ hi,
                                                   ushort* __restrict__ lo,
                                                   float* __restrict__ cbnorm) {
    int wave = threadIdx.x >> 6;
    int lane = threadIdx.x & 63;
    int k = blockIdx.x * 4 + wave;
    float4 v = *(const float4*)&cb[(size_t)k * D_DIM + lane * 4];
    ushort4 h, l;
    h.x = f2bf_rne(v.x); l.x = f2bf_rne(v.x - bf2f(h.x));
    h.y = f2bf_rne(v.y); l.y = f2bf_rne(v.y - bf2f(h.y));
    h.z = f2bf_rne(v.z); l.z = f2bf_rne(v.z - bf2f(h.z));
    h.w = f2bf_rne(v.w); l.w = f2bf_rne(v.w - bf2f(h.w));
    *(ushort4*)&hi[(size_t)k * D_DIM + lane * 4] = h;
    *(ushort4*)&lo[(size_t)k * D_DIM + lane * 4] = l;
    float s = v.x * v.x + v.y * v.y + v.z * v.z + v.w * v.w;
    #pragma unroll
    for (int off = 32; off >= 1; off >>= 1) s += __shfl_xor(s, off);
    if (lane == 0) cbnorm[k] = s;
}

// ============================================================
// ztrans: z (d-major) -> zhi/zlo bf16 (position-major).
__global__ __launch_bounds__(256) void ztrans_kernel(const float* __restrict__ z,
                                                     ushort* __restrict__ zhi,
                                                     ushort* __restrict__ zlo) {
    __shared__ float Zs[32][65];
    const int tid = threadIdx.x;
    const int n0  = blockIdx.x * 64;
    const int b   = n0 >> 10;
    const int hw0 = n0 & 1023;
    const float* zb = z + (size_t)b * (D_DIM * HW) + hw0;

    const int zn = tid & 63;
    const int zdb = (tid >> 6) * 8;
    const int n  = tid >> 2;
    const int dq = tid & 3;

    for (int d0 = 0; d0 < D_DIM; d0 += 32) {
        __syncthreads();
        #pragma unroll
        for (int j = 0; j < 8; ++j)
            Zs[zdb + j][zn] = zb[(size_t)(d0 + zdb + j) * HW + zn];
        __syncthreads();
        s16x8 hv, lv;
        #pragma unroll
        for (int j = 0; j < 8; ++j) {
            float f = Zs[dq * 8 + j][n];
            ushort hb = f2bf_rne(f);
            ushort lb = f2bf_rne(f - bf2f(hb));
            hv[j] = (short)hb;
            lv[j] = (short)lb;
        }
        *(s16x8*)&zhi[(size_t)(n0 + n) * D_DIM + d0 + dq * 8] = hv;
        *(s16x8*)&zlo[(size_t)(n0 + n) * D_DIM + d0 + dq * 8] = lv;
    }
}

// ============================================================
// argmin_gemm: 128 positions x 128 codes per block, 3-term bf16 MFMA,
// global_load_lds staging with source-side chunk swizzle. Partial argmin
// keys (dist<<32|code) written per (position, code-tile).
__global__ __launch_bounds__(256) void argmin_gemm(const ushort* __restrict__ cbhi,
                                                   const ushort* __restrict__ cblo,
                                                   const ushort* __restrict__ zhi,
                                                   const ushort* __restrict__ zlo,
                                                   const float* __restrict__ cbnorm,
                                                   u64* __restrict__ partial) {
    __shared__ ushort lds[16384];      // Ahi|Alo|Bhi|Blo, 4096 shorts each
    __shared__ u64 kred[128][2];

    const int tid  = threadIdx.x;
    const int wave = tid >> 6;
    const int lane = tid & 63;
    const int col  = lane & 15;
    const int lg   = lane >> 4;
    const int mt = blockIdx.x & 7;     // code tile (128 codes)
    const int pt = blockIdx.x >> 3;    // position tile (128 positions)
    const int ch = wave & 1;           // code half within block
    const int ph = wave >> 1;          // position half within block

    // staging source offsets (ushort units). Chunk swizzle lives in the
    // GLOBAL address so the LDS dst stays lane*16-contiguous.
    const int r0  = tid >> 2;                          // rows 0..63 (even issues)
    const int dch = (tid & 3) ^ ((r0 >> 1) & 3);
    const size_t eA0 = (size_t)(mt * 128 + r0) * D_DIM + dch * 8;
    const size_t eB0 = (size_t)(pt * 128 + r0) * D_DIM + dch * 8;
    const int ldsw = wave * 512;                       // wave-uniform lds offset

    // fragment read offsets: row r reads slot (lg ^ ((r>>1)&3)); for our rows
    // (r>>1)&3 == (col>>1)&3, uniform across mi/ni.
    const int swz = (lg ^ ((col >> 1) & 3)) * 8;
    const int soffA = (ch * 64 + col) * 32 + swz;
    const int soffB = (ph * 64 + col) * 32 + swz;

    f32x4 acc[4][4];
    #pragma unroll
    for (int mi = 0; mi < 4; ++mi)
        #pragma unroll
        for (int ni = 0; ni < 4; ++ni) acc[mi][ni] = {0.f, 0.f, 0.f, 0.f};

    for (int s8 = 0; s8 < 8; ++s8) {
        const int d0 = s8 * 32;
        __syncthreads();
        gload16(cbhi + eA0 + d0,            &lds[0     + ldsw]);
        gload16(cbhi + eA0 + 64 * 256 + d0, &lds[2048  + ldsw]);
        gload16(cblo + eA0 + d0,            &lds[4096  + ldsw]);
        gload16(cblo + eA0 + 64 * 256 + d0, &lds[6144  + ldsw]);
        gload16(zhi  + eB0 + d0,            &lds[8192  + ldsw]);
        gload16(zhi  + eB0 + 64 * 256 + d0, &lds[10240 + ldsw]);
        gload16(zlo  + eB0 + d0,            &lds[12288 + ldsw]);
        gload16(zlo  + eB0 + 64 * 256 + d0, &lds[14336 + ldsw]);
        __syncthreads();   // compiler drains vmcnt before s_barrier

        s16x8 ah[4], al[4], bh[4], bl[4];
        #pragma unroll
        for (int mi = 0; mi < 4; ++mi) {
            int so = soffA + mi * 512;
            ah[mi] = *(const s16x8*)&lds[so];
            al[mi] = *(const s16x8*)&lds[4096 + so];
        }
        #pragma unroll
        for (int ni = 0; ni < 4; ++ni) {
            int so = soffB + ni * 512;
            bh[ni] = *(const s16x8*)&lds[8192 + so];
            bl[ni] = *(const s16x8*)&lds[12288 + so];
        }
        #pragma unroll
        for (int mi = 0; mi < 4; ++mi)
            #pragma unroll
            for (int ni = 0; ni < 4; ++ni) {
                acc[mi][ni] = __builtin_amdgcn_mfma_f32_16x16x32_bf16(ah[mi], bh[ni], acc[mi][ni], 0, 0, 0);
                acc[mi][ni] = __builtin_amdgcn_mfma_f32_16x16x32_bf16(ah[mi], bl[ni], acc[mi][ni], 0, 0, 0);
                acc[mi][ni] = __builtin_amdgcn_mfma_f32_16x16x32_bf16(al[mi], bh[ni], acc[mi][ni], 0, 0, 0);
            }
    }

    // epilogue: fold 16x(4 regs) accs into per-position argmin keys
    const int kbase = mt * 128 + ch * 64;
    u64 best[4] = {~0ull, ~0ull, ~0ull, ~0ull};
    #pragma unroll
    for (int mi = 0; mi < 4; ++mi) {
        float4 cn = *(const float4*)&cbnorm[kbase + mi * 16 + lg * 4];
        const float* cnp = (const float*)&cn;
        #pragma unroll
        for (int ni = 0; ni < 4; ++ni) {
            #pragma unroll
            for (int r = 0; r < 4; ++r) {
                float dist = cnp[r] - 2.f * acc[mi][ni][r];
                uint ub = __float_as_uint(dist);
                ub = ub ^ (uint)(((int)ub >> 31) | 0x80000000);   // monotone f32->u32
                u64 key = ((u64)ub << 32) | (uint)(kbase + mi * 16 + lg * 4 + r);
                if (key < best[ni]) best[ni] = key;
            }
        }
    }
    #pragma unroll
    for (int ni = 0; ni < 4; ++ni) {
        u64 o = __shfl_xor(best[ni], 16); if (o < best[ni]) best[ni] = o;
        o = __shfl_xor(best[ni], 32); if (o < best[ni]) best[ni] = o;
    }
    if (lane < 16) {
        #pragma unroll
        for (int ni = 0; ni < 4; ++ni)
            kred[ph * 64 + ni * 16 + lane][ch] = best[ni];
    }
    __syncthreads();
    if (tid < 128) {
        u64 a = kred[tid][0], b = kred[tid][1];
        partial[(size_t)(pt * 128 + tid) * 8 + mt] = a < b ? a : b;
    }
}

// ============================================================
// combine: min over the 8 code-tile partials -> idx + counts histogram.
__global__ __launch_bounds__(256) void combine_kernel(const u64* __restrict__ partial,
                                                      int* __restrict__ idx,
                                                      float* __restrict__ counts) {
    int n = blockIdx.x * 256 + threadIdx.x;
    const u64* p = partial + (size_t)n * 8;
    u64 m = p[0];
    #pragma unroll
    for (int j = 1; j < 8; ++j) { u64 v = p[j]; if (v < m) m = v; }
    int k = (int)(m & 1023u);
    idx[n] = k;
    atomicAdd(&counts[k], 1.f);
}

// ============================================================
// small: new_cluster_size, perplexity, ntot, prefix-scan offsets/cursor.
__global__ __launch_bounds__(1024) void small_kernel(const float* __restrict__ ema_cs,
                                                     const float* __restrict__ counts,
                                                     float* __restrict__ out_ncs,
                                                     float* __restrict__ out_perp,
                                                     float* __restrict__ ntot_ws,
                                                     int* __restrict__ offsets,
                                                     int* __restrict__ cursor) {
    __shared__ float s1[1024];
    __shared__ float s2[1024];
    __shared__ int   s3[1024];
    int k = threadIdx.x;
    float cnt = counts[k];
    float ncs = ema_cs[k] * DECAY_F + ONE_M_DECAY * cnt;
    out_ncs[k] = ncs;
    float p = cnt / (float)N_POS;
    s1[k] = ncs;
    s2[k] = p * logf(p + 1e-10f);
    int c = (int)cnt;
    s3[k] = c;
    __syncthreads();
    for (int off = 1; off < 1024; off <<= 1) {
        int v = (k >= off) ? s3[k - off] : 0;
        __syncthreads();
        s3[k] += v;
        __syncthreads();
    }
    int excl = s3[k] - c;
    offsets[k] = excl;
    cursor[k] = excl;
    for (int st = 512; st >= 1; st >>= 1) {
        if (k < st) { s1[k] += s1[k + st]; s2[k] += s2[k + st]; }
        __syncthreads();
    }
    if (k == 0) {
        ntot_ws[0] = s1[0];
        out_perp[0] = expf(-s2[0]);
    }
}

// ============================================================
// scatter: bucket position ids by code.
__global__ __launch_bounds__(256) void scatter_kernel(const int* __restrict__ idx,
                                                      int* __restrict__ cursor,
                                                      int* __restrict__ sorted) {
    int n = blockIdx.x * 256 + threadIdx.x;
    int k = idx[n];
    int pos = atomicAdd(&cursor[k], 1);
    sorted[pos] = n;
}

// ============================================================
// dw: one block per code; segmented sum over sorted positions.
// z reconstructed as hi+lo (error ~2^-18 relative — negligible).
__global__ __launch_bounds__(256) void dw_kernel(const ushort* __restrict__ zhi,
                                                 const ushort* __restrict__ zlo,
                                                 const int* __restrict__ sorted,
                                                 const int* __restrict__ offsets,
                                                 const float* __restrict__ counts,
                                                 float* __restrict__ dw) {
    __shared__ float part[4][256];
    const int k = blockIdx.x;
    const int start = offsets[k];
    const int cnt = (int)counts[k];
    const int w = threadIdx.x >> 6;
    const int lane = threadIdx.x & 63;

    float4 acc = {0.f, 0.f, 0.f, 0.f};
    for (int p = start + w; p < start + cnt; p += 4) {
        int id = sorted[p];
        ushort4 h = *(const ushort4*)&zhi[(size_t)id * D_DIM + lane * 4];
        ushort4 l = *(const ushort4*)&zlo[(size_t)id * D_DIM + lane * 4];
        acc.x += bf2f(h.x) + bf2f(l.x);
        acc.y += bf2f(h.y) + bf2f(l.y);
        acc.z += bf2f(h.z) + bf2f(l.z);
        acc.w += bf2f(h.w) + bf2f(l.w);
    }
    part[w][lane * 4 + 0] = acc.x;
    part[w][lane * 4 + 1] = acc.y;
    part[w][lane * 4 + 2] = acc.z;
    part[w][lane * 4 + 3] = acc.w;
    __syncthreads();
    int d = threadIdx.x;
    dw[(size_t)k * D_DIM + d] = part[0][d] + part[1][d] + part[2][d] + part[3][d];
}

// ============================================================
// fuse: read z -> write outq (straight-through), accumulate loss.
// Runs AFTER dw (overwrites the zhi/zlo scratch living in OUT_Q).
__global__ __launch_bounds__(256) void fuse_kernel(const float* __restrict__ z,
                                                   const float* __restrict__ cb,
                                                   const int* __restrict__ idx,
                                                   float* __restrict__ outq,
                                                   float* __restrict__ lossacc) {
    __shared__ float Zs[32][65];
    __shared__ float Qs[32][65];
    __shared__ int kidx[64];
    __shared__ float red[256];

    const int tid = threadIdx.x;
    const int n0  = blockIdx.x * 64;
    const int b   = n0 >> 10;
    const int hw0 = n0 & 1023;
    const float* zb = z    + (size_t)b * (D_DIM * HW) + hw0;
    float*       ob = outq + (size_t)b * (D_DIM * HW) + hw0;

    if (tid < 64) kidx[tid] = idx[n0 + tid];

    const int zn = tid & 63;
    const int zdb = (tid >> 6) * 8;
    float loss = 0.f;

    for (int d0 = 0; d0 < D_DIM; d0 += 32) {
        __syncthreads();
        #pragma unroll
        for (int j = 0; j < 8; ++j)
            Zs[zdb + j][zn] = zb[(size_t)(d0 + zdb + j) * HW + zn];
        __syncthreads();

        #pragma unroll
        for (int h = 0; h < 2; ++h) {
            int s  = tid + 256 * h;
            int n  = s >> 3;
            int dq = s & 7;
            int k  = kidx[n];
            float4 q = *(const float4*)&cb[(size_t)k * D_DIM + d0 + dq * 4];
            float zx = Zs[dq * 4 + 0][n];
            float zy = Zs[dq * 4 + 1][n];
            float zz2 = Zs[dq * 4 + 2][n];
            float zw = Zs[dq * 4 + 3][n];
            Qs[dq * 4 + 0][n] = q.x;
            Qs[dq * 4 + 1][n] = q.y;
            Qs[dq * 4 + 2][n] = q.z;
            Qs[dq * 4 + 3][n] = q.w;
            float dx = zx - q.x, dy = zy - q.y, dz = zz2 - q.z, dww = zw - q.w;
            loss += dx * dx + dy * dy + dz * dz + dww * dww;
        }
        __syncthreads();

        #pragma unroll
        for (int j = 0; j < 8; ++j) {
            int v = tid + 256 * j;
            int d = v >> 6;
            int n = v & 63;
            float qq = Qs[d][n];
            float zval = Zs[d][n];
            ob[(size_t)(d0 + d) * HW + n] = zval + (qq - zval);
        }
    }

    red[tid] = loss;
    __syncthreads();
    for (int s2 = 128; s2 >= 1; s2 >>= 1) {
        if (tid < s2) red[tid] += red[tid + s2];
        __syncthreads();
    }
    if (tid == 0) atomicAdd(lossacc, red[0]);
}

// ============================================================
// finalize_rows: new_ema_dw (in place), new_codebook, and the loss scalar.
__global__ __launch_bounds__(256) void finalize_rows(const float* __restrict__ ema_dw,
                                                     const float* __restrict__ out_ncs,
                                                     const float* __restrict__ ntot_ws,
                                                     const float* __restrict__ lossacc,
                                                     float* __restrict__ out_edw,
                                                     float* __restrict__ out_cb,
                                                     float* __restrict__ out_loss) {
    int k = blockIdx.x;
    int d = threadIdx.x;
    float ncs = out_ncs[k];
    float nt = ntot_ws[0];
    float csz = (ncs + EPS_F) / (nt + (float)K_CODES * EPS_F) * nt;
    size_t e = (size_t)k * D_DIM + d;
    float ed = ema_dw[e] * DECAY_F + ONE_M_DECAY * out_edw[e];
    out_edw[e] = ed;
    out_cb[e] = ed / csz;
    if (k == 0 && d == 0) out_loss[0] = 0.25f * lossacc[0] / 8388608.0f;
}

// ============================================================
extern "C" void kernel_launch(void* const* d_in, const int* in_sizes, int n_in,
                              void* d_out, int out_size, void* d_ws, size_t ws_size,
                              hipStream_t stream) {
    const float* z       = (const float*)d_in[0];
    const float* cb      = (const float*)d_in[1];
    const float* ema_cs  = (const float*)d_in[2];
    const float* ema_dw  = (const float*)d_in[3];
    float* out = (float*)d_out;

    char* ws = (char*)d_ws;
    float* ws_counts = (float*)(ws + WS_COUNTS);
    float* ws_loss   = (float*)(ws + WS_LOSS);
    float* ws_ntot   = (float*)(ws + WS_NTOT);
    float* ws_cbnorm = (float*)(ws + WS_CBNORM);
    int*   ws_offs   = (int*)(ws + WS_OFFS);
    int*   ws_cursor = (int*)(ws + WS_CURSOR);
    int*   ws_idx    = (int*)(ws + WS_IDX);
    int*   ws_sorted = (int*)(ws + WS_SORTED);
    ushort* ws_cbhi  = (ushort*)(ws + WS_CBHI);
    ushort* ws_cblo  = (ushort*)(ws + WS_CBLO);
    u64*   ws_part   = (u64*)(ws + WS_PART);

    // zhi/zlo scratch lives in the OUT_Q region (exactly 32 MB)
    ushort* zhi = (ushort*)out;
    ushort* zlo = zhi + 8388608;

    hipMemsetAsync(d_ws, 0, WS_MEMSET, stream);

    prep_kernel<<<K_CODES / 4, 256, 0, stream>>>(cb, ws_cbhi, ws_cblo, ws_cbnorm);
    ztrans_kernel<<<N_POS / 64, 256, 0, stream>>>(z, zhi, zlo);
    argmin_gemm<<<2048, 256, 0, stream>>>(ws_cbhi, ws_cblo, zhi, zlo, ws_cbnorm, ws_part);
    combine_kernel<<<N_POS / 256, 256, 0, stream>>>(ws_part, ws_idx, ws_counts);
    small_kernel<<<1, 1024, 0, stream>>>(ema_cs, ws_counts, out + OUT_NCS,
                                         out + OUT_PERP, ws_ntot, ws_offs, ws_cursor);
    scatter_kernel<<<N_POS / 256, 256, 0, stream>>>(ws_idx, ws_cursor, ws_sorted);
    dw_kernel<<<K_CODES, 256, 0, stream>>>(zhi, zlo, ws_sorted, ws_offs, ws_counts,
                                           out + OUT_EDW);
    fuse_kernel<<<N_POS / 64, 256, 0, stream>>>(z, cb, ws_idx, out + OUT_Q, ws_loss);
    finalize_rows<<<K_CODES, 256, 0, stream>>>(ema_dw, out + OUT_NCS, ws_ntot, ws_loss,
                                               out + OUT_EDW, out + OUT_CB,
                                               out + OUT_LOSS);
}

// Round 5
// 234.450 us; speedup vs baseline: 2.7147x; 1.6754x over previous
//
#include <hip/hip_runtime.h>
#include <cfloat>
#include <cstdint>

// ---------------- problem constants ----------------
#define B_BATCH 32
#define D_DIM   256
#define HW      1024
#define N_POS   32768
#define K_CODES 1024
#define DECAY_F   0.99f
#define ONE_M_DECAY 0.01f
#define EPS_F   1e-5f

// ---------------- output layout (floats) ----------------
#define OUT_Q    0                         // 8388608  quantized_st (B,C,H,W)
#define OUT_LOSS 8388608                   // 1
#define OUT_PERP 8388609                   // 1
#define OUT_CB   8388610                   // 262144   new_codebook
#define OUT_NCS  8650754                   // 1024     new_cluster_size
#define OUT_EDW  8651778                   // 262144   new_ema_dw (dw scratch first)

// OUT_Q region doubles as z bf16 hi/lo scratch (exactly 33,554,432 bytes):
// ztrans writes zhi (16 MB) + zlo (16 MB); argmin_gemm + dw read them;
// fuse overwrites the region with the real output at the end.

// ---------------- workspace layout (bytes) ----------------
#define WS_COUNTS  0          // 1024*4
#define WS_LOSS    4096       // 4
#define WS_NTOT    4100       // 4
#define WS_MEMSET  4104       // bytes zeroed at launch
#define WS_CBNORM  4352       // 1024*4
#define WS_OFFS    8448       // 1024*4 (int)
#define WS_CURSOR  12544      // 1024*4 (int)
#define WS_IDX     16640      // 32768*4 (int)
#define WS_SORTED  147712     // 32768*4 (int)
#define WS_CBHI    278784     // 262144*2
#define WS_CBLO    803072     // 262144*2
#define WS_PART    1327360    // 32768*8*8 = 2097152 (u64 partial keys)
#define WS_SCODE   3424512    // 32768*4 (int, code of each sorted slot)
#define WS_TOTAL   3555584

typedef short s16x8 __attribute__((ext_vector_type(8)));
typedef float f32x4 __attribute__((ext_vector_type(4)));
typedef unsigned long long u64;

__device__ __forceinline__ ushort f2bf_rne(float x) {
    uint u = __float_as_uint(x);
    uint r = (u + 0x7FFF + ((u >> 16) & 1)) >> 16;
    return (ushort)r;
}
__device__ __forceinline__ float bf2f(ushort h) {
    return __uint_as_float(((uint)h) << 16);
}

// async global->LDS, 16 B per lane; LDS dst = wave-uniform base + lane*16
__device__ __forceinline__ void gload16(const void* g, void* l) {
    __builtin_amdgcn_global_load_lds(
        (const __attribute__((address_space(1))) unsigned*)(uintptr_t)g,
        (__attribute__((address_space(3))) unsigned*)(uintptr_t)l, 16, 0, 0);
}

// ============================================================
// prep: codebook fp32 -> bf16 hi/lo + row squared norms. One wave per code.
__global__ __launch_bounds__(256) void prep_kernel(const float* __restrict__ cb,
                                                   ushort* __restrict__ hi,
                                                   ushort* __restrict__ lo,
                                                   float* __restrict__ cbnorm) {
    int wave = threadIdx.x >> 6;
    int lane = threadIdx.x & 63;
    int k = blockIdx.x * 4 + wave;
    float4 v = *(const float4*)&cb[(size_t)k * D_DIM + lane * 4];
    ushort4 h, l;
    h.x = f2bf_rne(v.x); l.x = f2bf_rne(v.x - bf2f(h.x));
    h.y = f2bf_rne(v.y); l.y = f2bf_rne(v.y - bf2f(h.y));
    h.z = f2bf_rne(v.z); l.z = f2bf_rne(v.z - bf2f(h.z));
    h.w = f2bf_rne(v.w); l.w = f2bf_rne(v.w - bf2f(h.w));
    *(ushort4*)&hi[(size_t)k * D_DIM + lane * 4] = h;
    *(ushort4*)&lo[(size_t)k * D_DIM + lane * 4] = l;
    float s = v.x * v.x + v.y * v.y + v.z * v.z + v.w * v.w;
    #pragma unroll
    for (int off = 32; off >= 1; off >>= 1) s += __shfl_xor(s, off);
    if (lane == 0) cbnorm[k] = s;
}

// ============================================================
// ztrans: z (d-major) -> zhi/zlo bf16 (position-major).
__global__ __launch_bounds__(256) void ztrans_kernel(const float* __restrict__ z,
                                                     ushort* __restrict__ zhi,
                                                     ushort* __restrict__ zlo) {
    __shared__ float Zs[32][65];
    const int tid = threadIdx.x;
    const int n0  = blockIdx.x * 64;
    const int b   = n0 >> 10;
    const int hw0 = n0 & 1023;
    const float* zb = z + (size_t)b * (D_DIM * HW) + hw0;

    const int zn = tid & 63;
    const int zdb = (tid >> 6) * 8;
    const int n  = tid >> 2;
    const int dq = tid & 3;

    for (int d0 = 0; d0 < D_DIM; d0 += 32) {
        __syncthreads();
        #pragma unroll
        for (int j = 0; j < 8; ++j)
            Zs[zdb + j][zn] = zb[(size_t)(d0 + zdb + j) * HW + zn];
        __syncthreads();
        s16x8 hv, lv;
        #pragma unroll
        for (int j = 0; j < 8; ++j) {
            float f = Zs[dq * 8 + j][n];
            ushort hb = f2bf_rne(f);
            ushort lb = f2bf_rne(f - bf2f(hb));
            hv[j] = (short)hb;
            lv[j] = (short)lb;
        }
        *(s16x8*)&zhi[(size_t)(n0 + n) * D_DIM + d0 + dq * 8] = hv;
        *(s16x8*)&zlo[(size_t)(n0 + n) * D_DIM + d0 + dq * 8] = lv;
    }
}

// ============================================================
// argmin_gemm: 128 positions x 128 codes per block, 3-term bf16 MFMA,
// global_load_lds staging with source-side chunk swizzle. Partial argmin
// keys (dist<<32|code) written per (position, code-tile).
__global__ __launch_bounds__(256) void argmin_gemm(const ushort* __restrict__ cbhi,
                                                   const ushort* __restrict__ cblo,
                                                   const ushort* __restrict__ zhi,
                                                   const ushort* __restrict__ zlo,
                                                   const float* __restrict__ cbnorm,
                                                   u64* __restrict__ partial) {
    __shared__ ushort lds[16384];      // Ahi|Alo|Bhi|Blo, 4096 shorts each
    __shared__ u64 kred[128][2];

    const int tid  = threadIdx.x;
    const int wave = tid >> 6;
    const int lane = tid & 63;
    const int col  = lane & 15;
    const int lg   = lane >> 4;
    const int mt = blockIdx.x & 7;     // code tile (128 codes)
    const int pt = blockIdx.x >> 3;    // position tile (128 positions)
    const int ch = wave & 1;           // code half within block
    const int ph = wave >> 1;          // position half within block

    const int r0  = tid >> 2;
    const int dch = (tid & 3) ^ ((r0 >> 1) & 3);
    const size_t eA0 = (size_t)(mt * 128 + r0) * D_DIM + dch * 8;
    const size_t eB0 = (size_t)(pt * 128 + r0) * D_DIM + dch * 8;
    const int ldsw = wave * 512;

    const int swz = (lg ^ ((col >> 1) & 3)) * 8;
    const int soffA = (ch * 64 + col) * 32 + swz;
    const int soffB = (ph * 64 + col) * 32 + swz;

    f32x4 acc[4][4];
    #pragma unroll
    for (int mi = 0; mi < 4; ++mi)
        #pragma unroll
        for (int ni = 0; ni < 4; ++ni) acc[mi][ni] = {0.f, 0.f, 0.f, 0.f};

    for (int s8 = 0; s8 < 8; ++s8) {
        const int d0 = s8 * 32;
        __syncthreads();
        gload16(cbhi + eA0 + d0,            &lds[0     + ldsw]);
        gload16(cbhi + eA0 + 64 * 256 + d0, &lds[2048  + ldsw]);
        gload16(cblo + eA0 + d0,            &lds[4096  + ldsw]);
        gload16(cblo + eA0 + 64 * 256 + d0, &lds[6144  + ldsw]);
        gload16(zhi  + eB0 + d0,            &lds[8192  + ldsw]);
        gload16(zhi  + eB0 + 64 * 256 + d0, &lds[10240 + ldsw]);
        gload16(zlo  + eB0 + d0,            &lds[12288 + ldsw]);
        gload16(zlo  + eB0 + 64 * 256 + d0, &lds[14336 + ldsw]);
        __syncthreads();

        s16x8 ah[4], al[4], bh[4], bl[4];
        #pragma unroll
        for (int mi = 0; mi < 4; ++mi) {
            int so = soffA + mi * 512;
            ah[mi] = *(const s16x8*)&lds[so];
            al[mi] = *(const s16x8*)&lds[4096 + so];
        }
        #pragma unroll
        for (int ni = 0; ni < 4; ++ni) {
            int so = soffB + ni * 512;
            bh[ni] = *(const s16x8*)&lds[8192 + so];
            bl[ni] = *(const s16x8*)&lds[12288 + so];
        }
        #pragma unroll
        for (int mi = 0; mi < 4; ++mi)
            #pragma unroll
            for (int ni = 0; ni < 4; ++ni) {
                acc[mi][ni] = __builtin_amdgcn_mfma_f32_16x16x32_bf16(ah[mi], bh[ni], acc[mi][ni], 0, 0, 0);
                acc[mi][ni] = __builtin_amdgcn_mfma_f32_16x16x32_bf16(ah[mi], bl[ni], acc[mi][ni], 0, 0, 0);
                acc[mi][ni] = __builtin_amdgcn_mfma_f32_16x16x32_bf16(al[mi], bh[ni], acc[mi][ni], 0, 0, 0);
            }
    }

    const int kbase = mt * 128 + ch * 64;
    u64 best[4] = {~0ull, ~0ull, ~0ull, ~0ull};
    #pragma unroll
    for (int mi = 0; mi < 4; ++mi) {
        float4 cn = *(const float4*)&cbnorm[kbase + mi * 16 + lg * 4];
        const float* cnp = (const float*)&cn;
        #pragma unroll
        for (int ni = 0; ni < 4; ++ni) {
            #pragma unroll
            for (int r = 0; r < 4; ++r) {
                float dist = cnp[r] - 2.f * acc[mi][ni][r];
                uint ub = __float_as_uint(dist);
                ub = ub ^ (uint)(((int)ub >> 31) | 0x80000000);
                u64 key = ((u64)ub << 32) | (uint)(kbase + mi * 16 + lg * 4 + r);
                if (key < best[ni]) best[ni] = key;
            }
        }
    }
    #pragma unroll
    for (int ni = 0; ni < 4; ++ni) {
        u64 o = __shfl_xor(best[ni], 16); if (o < best[ni]) best[ni] = o;
        o = __shfl_xor(best[ni], 32); if (o < best[ni]) best[ni] = o;
    }
    if (lane < 16) {
        #pragma unroll
        for (int ni = 0; ni < 4; ++ni)
            kred[ph * 64 + ni * 16 + lane][ch] = best[ni];
    }
    __syncthreads();
    if (tid < 128) {
        u64 a = kred[tid][0], b = kred[tid][1];
        partial[(size_t)(pt * 128 + tid) * 8 + mt] = a < b ? a : b;
    }
}

// ============================================================
// combine: min over the 8 code-tile partials -> idx; LDS histogram then
// one global float-add per nonzero code (kills hot-address contention).
__global__ __launch_bounds__(256) void combine_kernel(const u64* __restrict__ partial,
                                                      int* __restrict__ idx,
                                                      float* __restrict__ counts) {
    __shared__ int hist[1024];
    const int tid = threadIdx.x;
    for (int j = tid; j < 1024; j += 256) hist[j] = 0;
    __syncthreads();
    int n = blockIdx.x * 256 + tid;
    const u64* p = partial + (size_t)n * 8;
    u64 m = p[0];
    #pragma unroll
    for (int j = 1; j < 8; ++j) { u64 v = p[j]; if (v < m) m = v; }
    int k = (int)(m & 1023u);
    idx[n] = k;
    atomicAdd(&hist[k], 1);
    __syncthreads();
    for (int j = tid; j < 1024; j += 256) {
        int c = hist[j];
        if (c) atomicAdd(&counts[j], (float)c);
    }
}

// ============================================================
// small: new_cluster_size, perplexity, ntot, prefix-scan offsets/cursor.
__global__ __launch_bounds__(1024) void small_kernel(const float* __restrict__ ema_cs,
                                                     const float* __restrict__ counts,
                                                     float* __restrict__ out_ncs,
                                                     float* __restrict__ out_perp,
                                                     float* __restrict__ ntot_ws,
                                                     int* __restrict__ offsets,
                                                     int* __restrict__ cursor) {
    __shared__ float s1[1024];
    __shared__ float s2[1024];
    __shared__ int   s3[1024];
    int k = threadIdx.x;
    float cnt = counts[k];
    float ncs = ema_cs[k] * DECAY_F + ONE_M_DECAY * cnt;
    out_ncs[k] = ncs;
    float p = cnt / (float)N_POS;
    s1[k] = ncs;
    s2[k] = p * logf(p + 1e-10f);
    int c = (int)cnt;
    s3[k] = c;
    __syncthreads();
    for (int off = 1; off < 1024; off <<= 1) {
        int v = (k >= off) ? s3[k - off] : 0;
        __syncthreads();
        s3[k] += v;
        __syncthreads();
    }
    int excl = s3[k] - c;
    offsets[k] = excl;
    cursor[k] = excl;
    for (int st = 512; st >= 1; st >>= 1) {
        if (k < st) { s1[k] += s1[k + st]; s2[k] += s2[k + st]; }
        __syncthreads();
    }
    if (k == 0) {
        ntot_ws[0] = s1[0];
        out_perp[0] = expf(-s2[0]);
    }
}

// ============================================================
// scatter: two-phase block-aggregated bucket sort. Emits sorted ids and
// their codes; global cursor atomics = one per distinct code per block.
__global__ __launch_bounds__(256) void scatter_kernel(const int* __restrict__ idx,
                                                      int* __restrict__ cursor,
                                                      int* __restrict__ sorted,
                                                      int* __restrict__ scode) {
    __shared__ int hist[1024];
    __shared__ int base_s[1024];
    const int tid = threadIdx.x;
    for (int j = tid; j < 1024; j += 256) hist[j] = 0;
    __syncthreads();
    int n = blockIdx.x * 256 + tid;
    int k = idx[n];
    atomicAdd(&hist[k], 1);
    __syncthreads();
    for (int j = tid; j < 1024; j += 256) {
        int c = hist[j];
        if (c) base_s[j] = atomicAdd(&cursor[j], c);
        hist[j] = 0;
    }
    __syncthreads();
    int rank = atomicAdd(&hist[k], 1);
    int pos = base_s[k] + rank;
    sorted[pos] = n;
    scode[pos] = k;
}

// ============================================================
// dw_chunk: uniform chunks of the SORTED array (load-balanced regardless of
// count skew). Thread t owns column d=t. Complete segments store directly;
// chunk-spanning runs use atomicAdd (<=2 per chunk). dw must be pre-zeroed.
#define DW_CHUNK 64
__global__ __launch_bounds__(256) void dw_chunk_kernel(const ushort* __restrict__ zhi,
                                                       const ushort* __restrict__ zlo,
                                                       const int* __restrict__ sorted,
                                                       const int* __restrict__ scode,
                                                       const int* __restrict__ offsets,
                                                       const float* __restrict__ counts,
                                                       float* __restrict__ dw) {
    __shared__ int sid[DW_CHUNK];
    __shared__ int sk[DW_CHUNK];
    const int tid = threadIdx.x;
    const int p0 = blockIdx.x * DW_CHUNK;
    if (tid < DW_CHUNK) {
        sid[tid] = sorted[p0 + tid];
        sk[tid]  = scode[p0 + tid];
    }
    __syncthreads();
    float acc = 0.f;
    int runstart = 0;
    #pragma unroll 4
    for (int i = 0; i < DW_CHUNK; ++i) {
        int id = sid[i];
        float zv = bf2f(zhi[(size_t)id * D_DIM + tid]) + bf2f(zlo[(size_t)id * D_DIM + tid]);
        acc += zv;
        bool end = (i == DW_CHUNK - 1) || (sk[i + 1] != sk[i]);
        if (end) {
            int k = sk[i];
            int off = offsets[k];
            int cnt = (int)counts[k];
            if (p0 + runstart == off && p0 + i == off + cnt - 1)
                dw[(size_t)k * D_DIM + tid] = acc;
            else
                atomicAdd(&dw[(size_t)k * D_DIM + tid], acc);
            acc = 0.f;
            runstart = i + 1;
        }
    }
}

// ============================================================
// fuse: read z -> write outq (straight-through), accumulate loss.
// Runs AFTER dw (overwrites the zhi/zlo scratch living in OUT_Q).
__global__ __launch_bounds__(256) void fuse_kernel(const float* __restrict__ z,
                                                   const float* __restrict__ cb,
                                                   const int* __restrict__ idx,
                                                   float* __restrict__ outq,
                                                   float* __restrict__ lossacc) {
    __shared__ float Zs[32][65];
    __shared__ float Qs[32][65];
    __shared__ int kidx[64];
    __shared__ float red[256];

    const int tid = threadIdx.x;
    const int n0  = blockIdx.x * 64;
    const int b   = n0 >> 10;
    const int hw0 = n0 & 1023;
    const float* zb = z    + (size_t)b * (D_DIM * HW) + hw0;
    float*       ob = outq + (size_t)b * (D_DIM * HW) + hw0;

    if (tid < 64) kidx[tid] = idx[n0 + tid];

    const int zn = tid & 63;
    const int zdb = (tid >> 6) * 8;
    float loss = 0.f;

    for (int d0 = 0; d0 < D_DIM; d0 += 32) {
        __syncthreads();
        #pragma unroll
        for (int j = 0; j < 8; ++j)
            Zs[zdb + j][zn] = zb[(size_t)(d0 + zdb + j) * HW + zn];
        __syncthreads();

        #pragma unroll
        for (int h = 0; h < 2; ++h) {
            int s  = tid + 256 * h;
            int n  = s >> 3;
            int dq = s & 7;
            int k  = kidx[n];
            float4 q = *(const float4*)&cb[(size_t)k * D_DIM + d0 + dq * 4];
            float zx = Zs[dq * 4 + 0][n];
            float zy = Zs[dq * 4 + 1][n];
            float zz2 = Zs[dq * 4 + 2][n];
            float zw = Zs[dq * 4 + 3][n];
            Qs[dq * 4 + 0][n] = q.x;
            Qs[dq * 4 + 1][n] = q.y;
            Qs[dq * 4 + 2][n] = q.z;
            Qs[dq * 4 + 3][n] = q.w;
            float dx = zx - q.x, dy = zy - q.y, dz = zz2 - q.z, dww = zw - q.w;
            loss += dx * dx + dy * dy + dz * dz + dww * dww;
        }
        __syncthreads();

        #pragma unroll
        for (int j = 0; j < 8; ++j) {
            int v = tid + 256 * j;
            int d = v >> 6;
            int n = v & 63;
            float qq = Qs[d][n];
            float zval = Zs[d][n];
            ob[(size_t)(d0 + d) * HW + n] = zval + (qq - zval);
        }
    }

    red[tid] = loss;
    __syncthreads();
    for (int s2 = 128; s2 >= 1; s2 >>= 1) {
        if (tid < s2) red[tid] += red[tid + s2];
        __syncthreads();
    }
    if (tid == 0) atomicAdd(lossacc, red[0]);
}

// ============================================================
// finalize_rows: new_ema_dw (in place), new_codebook, and the loss scalar.
__global__ __launch_bounds__(256) void finalize_rows(const float* __restrict__ ema_dw,
                                                     const float* __restrict__ out_ncs,
                                                     const float* __restrict__ ntot_ws,
                                                     const float* __restrict__ lossacc,
                                                     float* __restrict__ out_edw,
                                                     float* __restrict__ out_cb,
                                                     float* __restrict__ out_loss) {
    int k = blockIdx.x;
    int d = threadIdx.x;
    float ncs = out_ncs[k];
    float nt = ntot_ws[0];
    float csz = (ncs + EPS_F) / (nt + (float)K_CODES * EPS_F) * nt;
    size_t e = (size_t)k * D_DIM + d;
    float ed = ema_dw[e] * DECAY_F + ONE_M_DECAY * out_edw[e];
    out_edw[e] = ed;
    out_cb[e] = ed / csz;
    if (k == 0 && d == 0) out_loss[0] = 0.25f * lossacc[0] / 8388608.0f;
}

// ============================================================
extern "C" void kernel_launch(void* const* d_in, const int* in_sizes, int n_in,
                              void* d_out, int out_size, void* d_ws, size_t ws_size,
                              hipStream_t stream) {
    const float* z       = (const float*)d_in[0];
    const float* cb      = (const float*)d_in[1];
    const float* ema_cs  = (const float*)d_in[2];
    const float* ema_dw  = (const float*)d_in[3];
    float* out = (float*)d_out;

    char* ws = (char*)d_ws;
    float* ws_counts = (float*)(ws + WS_COUNTS);
    float* ws_loss   = (float*)(ws + WS_LOSS);
    float* ws_ntot   = (float*)(ws + WS_NTOT);
    float* ws_cbnorm = (float*)(ws + WS_CBNORM);
    int*   ws_offs   = (int*)(ws + WS_OFFS);
    int*   ws_cursor = (int*)(ws + WS_CURSOR);
    int*   ws_idx    = (int*)(ws + WS_IDX);
    int*   ws_sorted = (int*)(ws + WS_SORTED);
    ushort* ws_cbhi  = (ushort*)(ws + WS_CBHI);
    ushort* ws_cblo  = (ushort*)(ws + WS_CBLO);
    u64*   ws_part   = (u64*)(ws + WS_PART);
    int*   ws_scode  = (int*)(ws + WS_SCODE);

    // zhi/zlo scratch lives in the OUT_Q region (exactly 32 MB)
    ushort* zhi = (ushort*)out;
    ushort* zlo = zhi + 8388608;

    hipMemsetAsync(d_ws, 0, WS_MEMSET, stream);
    hipMemsetAsync(out + OUT_EDW, 0, K_CODES * D_DIM * sizeof(float), stream);

    prep_kernel<<<K_CODES / 4, 256, 0, stream>>>(cb, ws_cbhi, ws_cblo, ws_cbnorm);
    ztrans_kernel<<<N_POS / 64, 256, 0, stream>>>(z, zhi, zlo);
    argmin_gemm<<<2048, 256, 0, stream>>>(ws_cbhi, ws_cblo, zhi, zlo, ws_cbnorm, ws_part);
    combine_kernel<<<N_POS / 256, 256, 0, stream>>>(ws_part, ws_idx, ws_counts);
    small_kernel<<<1, 1024, 0, stream>>>(ema_cs, ws_counts, out + OUT_NCS,
                                         out + OUT_PERP, ws_ntot, ws_offs, ws_cursor);
    scatter_kernel<<<N_POS / 256, 256, 0, stream>>>(ws_idx, ws_cursor, ws_sorted, ws_scode);
    dw_chunk_kernel<<<N_POS / DW_CHUNK, 256, 0, stream>>>(zhi, zlo, ws_sorted, ws_scode,
                                                          ws_offs, ws_counts, out + OUT_EDW);
    fuse_kernel<<<N_POS / 64, 256, 0, stream>>>(z, cb, ws_idx, out + OUT_Q, ws_loss);
    finalize_rows<<<K_CODES, 256, 0, stream>>>(ema_dw, out + OUT_NCS, ws_ntot, ws_loss,
                                               out + OUT_EDW, out + OUT_CB,
                                               out + OUT_LOSS);
}

// Round 6
// 213.931 us; speedup vs baseline: 2.9751x; 1.0959x over previous
//
#include <hip/hip_runtime.h>
#include <cfloat>
#include <cstdint>

// ---------------- problem constants ----------------
#define B_BATCH 32
#define D_DIM   256
#define HW      1024
#define N_POS   32768
#define K_CODES 1024
#define DECAY_F   0.99f
#define ONE_M_DECAY 0.01f
#define EPS_F   1e-5f

// ---------------- output layout (floats) ----------------
#define OUT_Q    0                         // 8388608  quantized_st (B,C,H,W)
#define OUT_LOSS 8388608                   // 1
#define OUT_PERP 8388609                   // 1
#define OUT_CB   8388610                   // 262144   new_codebook
#define OUT_NCS  8650754                   // 1024     new_cluster_size
#define OUT_EDW  8651778                   // 262144   new_ema_dw (dw scratch first)

// OUT_Q region doubles as z bf16 hi/lo scratch (exactly 33,554,432 bytes):
// ztrans writes zhi (16 MB) + zlo (16 MB); argmin_gemm + dw read them;
// fuse overwrites the region with the real output at the end.

// ---------------- workspace layout (bytes) ----------------
#define WS_COUNTS  0          // 1024*4
#define WS_ZNORM   4096       // 4   (sum of ||z||^2, fp32)
#define WS_BSUM    4100       // 4   (sum of best distances)
#define WS_MEMSET  4104       // bytes zeroed at launch
#define WS_CBNORM  4352       // 1024*4
#define WS_OFFS    8448       // 1024*4 (int)
#define WS_CURSOR  12544      // 1024*4 (int)
#define WS_IDX     16640      // 32768*4 (int)
#define WS_SORTED  147712     // 32768*4 (int)
#define WS_CBHI    278784     // 262144*2
#define WS_CBLO    803072     // 262144*2
#define WS_PART    1327360    // 32768*8*8 = 2097152 (u64 partial keys)
#define WS_SCODE   3424512    // 32768*4 (int, code of each sorted slot)
#define WS_TOTAL   3555584

typedef short s16x8 __attribute__((ext_vector_type(8)));
typedef float f32x4 __attribute__((ext_vector_type(4)));
typedef unsigned long long u64;

__device__ __forceinline__ ushort f2bf_rne(float x) {
    uint u = __float_as_uint(x);
    uint r = (u + 0x7FFF + ((u >> 16) & 1)) >> 16;
    return (ushort)r;
}
__device__ __forceinline__ float bf2f(ushort h) {
    return __uint_as_float(((uint)h) << 16);
}

// async global->LDS, 16 B per lane; LDS dst = wave-uniform base + lane*16
__device__ __forceinline__ void gload16(const void* g, void* l) {
    __builtin_amdgcn_global_load_lds(
        (const __attribute__((address_space(1))) unsigned*)(uintptr_t)g,
        (__attribute__((address_space(3))) unsigned*)(uintptr_t)l, 16, 0, 0);
}

// ============================================================
// prep_ztrans: fused.
//  blocks [0,512):  z (d-major) -> zhi/zlo bf16 (position-major) + sum ||z||^2
//  blocks [512,768): codebook fp32 -> bf16 hi/lo + row norms
__global__ __launch_bounds__(256) void prep_ztrans(const float* __restrict__ z,
                                                   const float* __restrict__ cb,
                                                   ushort* __restrict__ zhi,
                                                   ushort* __restrict__ zlo,
                                                   ushort* __restrict__ cbhi,
                                                   ushort* __restrict__ cblo,
                                                   float* __restrict__ cbnorm,
                                                   float* __restrict__ znorm_acc) {
    __shared__ float Zs[32][65];
    __shared__ float red[256];
    const int tid = threadIdx.x;

    if (blockIdx.x >= 512) {   // ---- prep part ----
        int wave = tid >> 6;
        int lane = tid & 63;
        int k = (blockIdx.x - 512) * 4 + wave;
        float4 v = *(const float4*)&cb[(size_t)k * D_DIM + lane * 4];
        ushort4 h, l;
        h.x = f2bf_rne(v.x); l.x = f2bf_rne(v.x - bf2f(h.x));
        h.y = f2bf_rne(v.y); l.y = f2bf_rne(v.y - bf2f(h.y));
        h.z = f2bf_rne(v.z); l.z = f2bf_rne(v.z - bf2f(h.z));
        h.w = f2bf_rne(v.w); l.w = f2bf_rne(v.w - bf2f(h.w));
        *(ushort4*)&cbhi[(size_t)k * D_DIM + lane * 4] = h;
        *(ushort4*)&cblo[(size_t)k * D_DIM + lane * 4] = l;
        float s = v.x * v.x + v.y * v.y + v.z * v.z + v.w * v.w;
        #pragma unroll
        for (int off = 32; off >= 1; off >>= 1) s += __shfl_xor(s, off);
        if (lane == 0) cbnorm[k] = s;
        return;
    }

    // ---- ztrans part ----
    const int n0  = blockIdx.x * 64;
    const int b   = n0 >> 10;
    const int hw0 = n0 & 1023;
    const float* zb = z + (size_t)b * (D_DIM * HW) + hw0;

    const int zn = tid & 63;
    const int zdb = (tid >> 6) * 8;
    const int n  = tid >> 2;
    const int dq = tid & 3;
    float zsum = 0.f;

    for (int d0 = 0; d0 < D_DIM; d0 += 32) {
        __syncthreads();
        #pragma unroll
        for (int j = 0; j < 8; ++j)
            Zs[zdb + j][zn] = zb[(size_t)(d0 + zdb + j) * HW + zn];
        __syncthreads();
        s16x8 hv, lv;
        #pragma unroll
        for (int j = 0; j < 8; ++j) {
            float f = Zs[dq * 8 + j][n];
            zsum += f * f;
            ushort hb = f2bf_rne(f);
            ushort lb = f2bf_rne(f - bf2f(hb));
            hv[j] = (short)hb;
            lv[j] = (short)lb;
        }
        *(s16x8*)&zhi[(size_t)(n0 + n) * D_DIM + d0 + dq * 8] = hv;
        *(s16x8*)&zlo[(size_t)(n0 + n) * D_DIM + d0 + dq * 8] = lv;
    }
    red[tid] = zsum;
    __syncthreads();
    for (int s2 = 128; s2 >= 1; s2 >>= 1) {
        if (tid < s2) red[tid] += red[tid + s2];
        __syncthreads();
    }
    if (tid == 0) atomicAdd(znorm_acc, red[0]);
}

// ============================================================
// argmin_gemm: 128 positions x 128 codes per block, 3-term bf16 MFMA.
// XCD-aware swizzle: the 8 code-tile blocks of one position-tile share
// blockIdx&7 (same XCD under round-robin dispatch) so the z tile stays
// resident in that XCD's L2 across all 8 code tiles.
__global__ __launch_bounds__(256) void argmin_gemm(const ushort* __restrict__ cbhi,
                                                   const ushort* __restrict__ cblo,
                                                   const ushort* __restrict__ zhi,
                                                   const ushort* __restrict__ zlo,
                                                   const float* __restrict__ cbnorm,
                                                   u64* __restrict__ partial) {
    __shared__ ushort lds[16384];      // Ahi|Alo|Bhi|Blo, 4096 shorts each
    __shared__ u64 kred[128][2];

    const int tid  = threadIdx.x;
    const int wave = tid >> 6;
    const int lane = tid & 63;
    const int col  = lane & 15;
    const int lg   = lane >> 4;
    const int blk = blockIdx.x;
    const int mt = (blk >> 3) & 7;                       // code tile
    const int pt = (blk & 7) | ((blk >> 6) << 3);        // position tile
    const int ch = wave & 1;
    const int ph = wave >> 1;

    const int r0  = tid >> 2;
    const int dch = (tid & 3) ^ ((r0 >> 1) & 3);
    const size_t eA0 = (size_t)(mt * 128 + r0) * D_DIM + dch * 8;
    const size_t eB0 = (size_t)(pt * 128 + r0) * D_DIM + dch * 8;
    const int ldsw = wave * 512;

    const int swz = (lg ^ ((col >> 1) & 3)) * 8;
    const int soffA = (ch * 64 + col) * 32 + swz;
    const int soffB = (ph * 64 + col) * 32 + swz;

    f32x4 acc[4][4];
    #pragma unroll
    for (int mi = 0; mi < 4; ++mi)
        #pragma unroll
        for (int ni = 0; ni < 4; ++ni) acc[mi][ni] = {0.f, 0.f, 0.f, 0.f};

    for (int s8 = 0; s8 < 8; ++s8) {
        const int d0 = s8 * 32;
        __syncthreads();
        gload16(cbhi + eA0 + d0,            &lds[0     + ldsw]);
        gload16(cbhi + eA0 + 64 * 256 + d0, &lds[2048  + ldsw]);
        gload16(cblo + eA0 + d0,            &lds[4096  + ldsw]);
        gload16(cblo + eA0 + 64 * 256 + d0, &lds[6144  + ldsw]);
        gload16(zhi  + eB0 + d0,            &lds[8192  + ldsw]);
        gload16(zhi  + eB0 + 64 * 256 + d0, &lds[10240 + ldsw]);
        gload16(zlo  + eB0 + d0,            &lds[12288 + ldsw]);
        gload16(zlo  + eB0 + 64 * 256 + d0, &lds[14336 + ldsw]);
        __syncthreads();

        s16x8 ah[4], al[4], bh[4], bl[4];
        #pragma unroll
        for (int mi = 0; mi < 4; ++mi) {
            int so = soffA + mi * 512;
            ah[mi] = *(const s16x8*)&lds[so];
            al[mi] = *(const s16x8*)&lds[4096 + so];
        }
        #pragma unroll
        for (int ni = 0; ni < 4; ++ni) {
            int so = soffB + ni * 512;
            bh[ni] = *(const s16x8*)&lds[8192 + so];
            bl[ni] = *(const s16x8*)&lds[12288 + so];
        }
        #pragma unroll
        for (int mi = 0; mi < 4; ++mi)
            #pragma unroll
            for (int ni = 0; ni < 4; ++ni) {
                acc[mi][ni] = __builtin_amdgcn_mfma_f32_16x16x32_bf16(ah[mi], bh[ni], acc[mi][ni], 0, 0, 0);
                acc[mi][ni] = __builtin_amdgcn_mfma_f32_16x16x32_bf16(ah[mi], bl[ni], acc[mi][ni], 0, 0, 0);
                acc[mi][ni] = __builtin_amdgcn_mfma_f32_16x16x32_bf16(al[mi], bh[ni], acc[mi][ni], 0, 0, 0);
            }
    }

    const int kbase = mt * 128 + ch * 64;
    u64 best[4] = {~0ull, ~0ull, ~0ull, ~0ull};
    #pragma unroll
    for (int mi = 0; mi < 4; ++mi) {
        float4 cn = *(const float4*)&cbnorm[kbase + mi * 16 + lg * 4];
        const float* cnp = (const float*)&cn;
        #pragma unroll
        for (int ni = 0; ni < 4; ++ni) {
            #pragma unroll
            for (int r = 0; r < 4; ++r) {
                float dist = cnp[r] - 2.f * acc[mi][ni][r];
                uint ub = __float_as_uint(dist);
                ub = ub ^ (uint)(((int)ub >> 31) | 0x80000000);
                u64 key = ((u64)ub << 32) | (uint)(kbase + mi * 16 + lg * 4 + r);
                if (key < best[ni]) best[ni] = key;
            }
        }
    }
    #pragma unroll
    for (int ni = 0; ni < 4; ++ni) {
        u64 o = __shfl_xor(best[ni], 16); if (o < best[ni]) best[ni] = o;
        o = __shfl_xor(best[ni], 32); if (o < best[ni]) best[ni] = o;
    }
    if (lane < 16) {
        #pragma unroll
        for (int ni = 0; ni < 4; ++ni)
            kred[ph * 64 + ni * 16 + lane][ch] = best[ni];
    }
    __syncthreads();
    if (tid < 128) {
        u64 a = kred[tid][0], b = kred[tid][1];
        partial[(size_t)(pt * 128 + tid) * 8 + mt] = a < b ? a : b;
    }
}

// ============================================================
// combine: min over 8 code-tile partials -> idx; LDS histogram -> counts;
// decode best distance -> block sum -> Sum(bestd) for the loss.
__global__ __launch_bounds__(256) void combine_kernel(const u64* __restrict__ partial,
                                                      int* __restrict__ idx,
                                                      float* __restrict__ counts,
                                                      float* __restrict__ bsum_acc) {
    __shared__ int hist[1024];
    __shared__ float red[256];
    const int tid = threadIdx.x;
    for (int j = tid; j < 1024; j += 256) hist[j] = 0;
    __syncthreads();
    int n = blockIdx.x * 256 + tid;
    const u64* p = partial + (size_t)n * 8;
    u64 m = p[0];
    #pragma unroll
    for (int j = 1; j < 8; ++j) { u64 v = p[j]; if (v < m) m = v; }
    int k = (int)(m & 1023u);
    idx[n] = k;
    atomicAdd(&hist[k], 1);
    // decode monotone u32 -> f32 distance
    uint ub = (uint)(m >> 32);
    uint u = (ub & 0x80000000u) ? (ub ^ 0x80000000u) : ~ub;
    red[tid] = __uint_as_float(u);
    __syncthreads();
    for (int s2 = 128; s2 >= 1; s2 >>= 1) {
        if (tid < s2) red[tid] += red[tid + s2];
        __syncthreads();
    }
    if (tid == 0) atomicAdd(bsum_acc, red[0]);
    for (int j = tid; j < 1024; j += 256) {
        int c = hist[j];
        if (c) atomicAdd(&counts[j], (float)c);
    }
}

// ============================================================
// small: new_cluster_size, perplexity, ntot, loss, prefix-scan offsets/cursor.
__global__ __launch_bounds__(1024) void small_kernel(const float* __restrict__ ema_cs,
                                                     const float* __restrict__ counts,
                                                     const float* __restrict__ znorm,
                                                     const float* __restrict__ bsum,
                                                     float* __restrict__ out_ncs,
                                                     float* __restrict__ out_perp,
                                                     float* __restrict__ out_loss,
                                                     float* __restrict__ ntot_ws,
                                                     int* __restrict__ offsets,
                                                     int* __restrict__ cursor) {
    __shared__ float s1[1024];
    __shared__ float s2[1024];
    __shared__ int   s3[1024];
    int k = threadIdx.x;
    float cnt = counts[k];
    float ncs = ema_cs[k] * DECAY_F + ONE_M_DECAY * cnt;
    out_ncs[k] = ncs;
    float p = cnt / (float)N_POS;
    s1[k] = ncs;
    s2[k] = p * logf(p + 1e-10f);
    int c = (int)cnt;
    s3[k] = c;
    __syncthreads();
    for (int off = 1; off < 1024; off <<= 1) {
        int v = (k >= off) ? s3[k - off] : 0;
        __syncthreads();
        s3[k] += v;
        __syncthreads();
    }
    int excl = s3[k] - c;
    offsets[k] = excl;
    cursor[k] = excl;
    for (int st = 512; st >= 1; st >>= 1) {
        if (k < st) { s1[k] += s1[k + st]; s2[k] += s2[k + st]; }
        __syncthreads();
    }
    if (k == 0) {
        ntot_ws[0] = s1[0];
        out_perp[0] = expf(-s2[0]);
        out_loss[0] = 0.25f * (znorm[0] + bsum[0]) / 8388608.0f;
    }
}

// ============================================================
// scatter: block-aggregated bucket sort; also zeroes the dw scratch region.
__global__ __launch_bounds__(256) void scatter_kernel(const int* __restrict__ idx,
                                                      int* __restrict__ cursor,
                                                      int* __restrict__ sorted,
                                                      int* __restrict__ scode,
                                                      float* __restrict__ dw_zero) {
    __shared__ int hist[1024];
    __shared__ int base_s[1024];
    const int tid = threadIdx.x;
    // zero the dw scratch (262144 floats / 128 blocks = 8 per thread)
    {
        float4 z4 = {0.f, 0.f, 0.f, 0.f};
        size_t e = ((size_t)blockIdx.x * 256 + tid) * 8;
        *(float4*)&dw_zero[e] = z4;
        *(float4*)&dw_zero[e + 4] = z4;
    }
    for (int j = tid; j < 1024; j += 256) hist[j] = 0;
    __syncthreads();
    int n = blockIdx.x * 256 + tid;
    int k = idx[n];
    atomicAdd(&hist[k], 1);
    __syncthreads();
    for (int j = tid; j < 1024; j += 256) {
        int c = hist[j];
        if (c) base_s[j] = atomicAdd(&cursor[j], c);
        hist[j] = 0;
    }
    __syncthreads();
    int rank = atomicAdd(&hist[k], 1);
    int pos = base_s[k] + rank;
    sorted[pos] = n;
    scode[pos] = k;
}

// ============================================================
// dw_chunk: uniform chunks of the SORTED array. Complete segments store
// directly; chunk-spanning runs atomicAdd. dw pre-zeroed by scatter.
#define DW_CHUNK 64
__global__ __launch_bounds__(256) void dw_chunk_kernel(const ushort* __restrict__ zhi,
                                                       const ushort* __restrict__ zlo,
                                                       const int* __restrict__ sorted,
                                                       const int* __restrict__ scode,
                                                       const int* __restrict__ offsets,
                                                       const float* __restrict__ counts,
                                                       float* __restrict__ dw) {
    __shared__ int sid[DW_CHUNK];
    __shared__ int sk[DW_CHUNK];
    const int tid = threadIdx.x;
    const int p0 = blockIdx.x * DW_CHUNK;
    if (tid < DW_CHUNK) {
        sid[tid] = sorted[p0 + tid];
        sk[tid]  = scode[p0 + tid];
    }
    __syncthreads();
    float acc = 0.f;
    int runstart = 0;
    #pragma unroll 4
    for (int i = 0; i < DW_CHUNK; ++i) {
        int id = sid[i];
        float zv = bf2f(zhi[(size_t)id * D_DIM + tid]) + bf2f(zlo[(size_t)id * D_DIM + tid]);
        acc += zv;
        bool end = (i == DW_CHUNK - 1) || (sk[i + 1] != sk[i]);
        if (end) {
            int k = sk[i];
            int off = offsets[k];
            int cnt = (int)counts[k];
            if (p0 + runstart == off && p0 + i == off + cnt - 1)
                dw[(size_t)k * D_DIM + tid] = acc;
            else
                atomicAdd(&dw[(size_t)k * D_DIM + tid], acc);
            acc = 0.f;
            runstart = i + 1;
        }
    }
}

// ============================================================
// fuse_lite: gather codebook rows -> outq in d-major layout. No z read:
// zp + (q - zp) == q to within 1 ulp, far below threshold.
__global__ __launch_bounds__(256) void fuse_lite(const float* __restrict__ cb,
                                                 const int* __restrict__ idx,
                                                 float* __restrict__ outq) {
    __shared__ float Qs[32][65];
    __shared__ int kidx[64];
    const int tid = threadIdx.x;
    const int n0  = blockIdx.x * 64;
    const int b   = n0 >> 10;
    const int hw0 = n0 & 1023;
    float* ob = outq + (size_t)b * (D_DIM * HW) + hw0;

    if (tid < 64) kidx[tid] = idx[n0 + tid];

    for (int d0 = 0; d0 < D_DIM; d0 += 32) {
        __syncthreads();   // protects Qs reuse (and kidx on first iter)
        #pragma unroll
        for (int h = 0; h < 2; ++h) {
            int s  = tid + 256 * h;
            int n  = s >> 3;
            int dq = s & 7;
            int k  = kidx[n];
            float4 q = *(const float4*)&cb[(size_t)k * D_DIM + d0 + dq * 4];
            Qs[dq * 4 + 0][n] = q.x;
            Qs[dq * 4 + 1][n] = q.y;
            Qs[dq * 4 + 2][n] = q.z;
            Qs[dq * 4 + 3][n] = q.w;
        }
        __syncthreads();
        #pragma unroll
        for (int j = 0; j < 8; ++j) {
            int v = tid + 256 * j;
            int d = v >> 6;
            int n = v & 63;
            ob[(size_t)(d0 + d) * HW + n] = Qs[d][n];
        }
    }
}

// ============================================================
// finalize_rows: new_ema_dw (in place) and new_codebook.
__global__ __launch_bounds__(256) void finalize_rows(const float* __restrict__ ema_dw,
                                                     const float* __restrict__ out_ncs,
                                                     const float* __restrict__ ntot_ws,
                                                     float* __restrict__ out_edw,
                                                     float* __restrict__ out_cb) {
    int k = blockIdx.x;
    int d = threadIdx.x;
    float ncs = out_ncs[k];
    float nt = ntot_ws[0];
    float csz = (ncs + EPS_F) / (nt + (float)K_CODES * EPS_F) * nt;
    size_t e = (size_t)k * D_DIM + d;
    float ed = ema_dw[e] * DECAY_F + ONE_M_DECAY * out_edw[e];
    out_edw[e] = ed;
    out_cb[e] = ed / csz;
}

// ============================================================
extern "C" void kernel_launch(void* const* d_in, const int* in_sizes, int n_in,
                              void* d_out, int out_size, void* d_ws, size_t ws_size,
                              hipStream_t stream) {
    const float* z       = (const float*)d_in[0];
    const float* cb      = (const float*)d_in[1];
    const float* ema_cs  = (const float*)d_in[2];
    const float* ema_dw  = (const float*)d_in[3];
    float* out = (float*)d_out;

    char* ws = (char*)d_ws;
    float* ws_counts = (float*)(ws + WS_COUNTS);
    float* ws_znorm  = (float*)(ws + WS_ZNORM);
    float* ws_bsum   = (float*)(ws + WS_BSUM);
    float* ws_cbnorm = (float*)(ws + WS_CBNORM);
    int*   ws_offs   = (int*)(ws + WS_OFFS);
    int*   ws_cursor = (int*)(ws + WS_CURSOR);
    int*   ws_idx    = (int*)(ws + WS_IDX);
    int*   ws_sorted = (int*)(ws + WS_SORTED);
    ushort* ws_cbhi  = (ushort*)(ws + WS_CBHI);
    ushort* ws_cblo  = (ushort*)(ws + WS_CBLO);
    u64*   ws_part   = (u64*)(ws + WS_PART);
    int*   ws_scode  = (int*)(ws + WS_SCODE);

    // zhi/zlo scratch lives in the OUT_Q region (exactly 32 MB)
    ushort* zhi = (ushort*)out;
    ushort* zlo = zhi + 8388608;

    hipMemsetAsync(d_ws, 0, WS_MEMSET, stream);

    prep_ztrans<<<768, 256, 0, stream>>>(z, cb, zhi, zlo, ws_cbhi, ws_cblo,
                                         ws_cbnorm, ws_znorm);
    argmin_gemm<<<2048, 256, 0, stream>>>(ws_cbhi, ws_cblo, zhi, zlo, ws_cbnorm, ws_part);
    combine_kernel<<<N_POS / 256, 256, 0, stream>>>(ws_part, ws_idx, ws_counts, ws_bsum);
    small_kernel<<<1, 1024, 0, stream>>>(ema_cs, ws_counts, ws_znorm, ws_bsum,
                                         out + OUT_NCS, out + OUT_PERP, out + OUT_LOSS,
                                         (float*)(ws + WS_ZNORM) + 1024, ws_offs, ws_cursor);
    // NOTE: ntot scratch must not alias anything live; reuse WS area after BSUM:
    // (ws + WS_ZNORM) + 1024 floats lands inside WS_CBNORM region? No — keep it
    // simple and safe: ntot goes to ws_bsum+... see below. (Overridden here:)
    scatter_kernel<<<N_POS / 256, 256, 0, stream>>>(ws_idx, ws_cursor, ws_sorted,
                                                    ws_scode, out + OUT_EDW);
    dw_chunk_kernel<<<N_POS / DW_CHUNK, 256, 0, stream>>>(zhi, zlo, ws_sorted, ws_scode,
                                                          ws_offs, ws_counts, out + OUT_EDW);
    fuse_lite<<<N_POS / 64, 256, 0, stream>>>(cb, ws_idx, out + OUT_Q);
    finalize_rows<<<K_CODES, 256, 0, stream>>>(ema_dw, out + OUT_NCS,
                                               (float*)(ws + WS_ZNORM) + 1024,
                                               out + OUT_EDW, out + OUT_CB);
}